// Round 8
// baseline (212168.530 us; speedup 1.0000x reference)
//
#include <hip/hip_runtime.h>

#define T_STEPS 24000
#define DIN 598
#define NU 100     // hidden units
#define NG 400     // 4 * NU gates
#define CHUNK 120  // steps per pipeline chunk
#define NCHUNK 200
#define RING 8     // ring capacity in chunks
#define RN (RING * CHUNK)   // 960 ring rows

// LDS-only barrier: orders ds ops without draining global loads/stores.
#define BARRIER_LDS() asm volatile("s_waitcnt lgkmcnt(0)\n\ts_barrier" ::: "memory")

// ---------------------------------------------------------------------------
// cross-WG sync helpers (device-scope; per-XCD L2s are non-coherent)
// ---------------------------------------------------------------------------
__device__ __forceinline__ void wg_wait_ge(int* flag, int target) {
    if (threadIdx.x == 0) {
        while (__hip_atomic_load(flag, __ATOMIC_RELAXED, __HIP_MEMORY_SCOPE_AGENT) < target)
            __builtin_amdgcn_s_sleep(2);
    }
    __syncthreads();
    __builtin_amdgcn_fence(__ATOMIC_ACQUIRE, "agent");
}
__device__ __forceinline__ void wg_publish(int* a, int va, int* b, int vb) {
    __syncthreads();
    if (threadIdx.x == 0) {
        if (a) __hip_atomic_store(a, va, __ATOMIC_RELEASE, __HIP_MEMORY_SCOPE_AGENT);
        if (b) __hip_atomic_store(b, vb, __ATOMIC_RELEASE, __HIP_MEMORY_SCOPE_AGENT);
    }
}

// ---------------------------------------------------------------------------
__device__ __forceinline__ float sigmoid_(float x) {
    return 1.f / (1.f + __expf(-x));
}
__device__ __forceinline__ float tanh_(float x) {
    float e = __expf(2.f * x);
    return 1.f - 2.f / (e + 1.f);
}

// ---------------------------------------------------------------------------
// GEMM with bias: C[M,N] = A[M,K] @ B[K,N] + bias[N]   (fp32, 64x64 tile)
// Writes PERMUTED columns: col n=(g*100+u) lands at u*4+g, so the rec role
// reads one coalesced float4 of (i,f,g,o) per unit per step.
// ---------------------------------------------------------------------------
__global__ __launch_bounds__(256) void gemm_bias_kernel(
    const float* __restrict__ A, const float* __restrict__ B,
    const float* __restrict__ bias, float* __restrict__ C,
    int M, int N, int K)
{
    __shared__ float As[16][65];
    __shared__ float Bs[16][65];
    const int tid = threadIdx.x;
    const int tx = tid & 15;
    const int ty = tid >> 4;
    const int bm = blockIdx.y * 64;
    const int bn = blockIdx.x * 64;
    float acc[4][4] = {};

    for (int k0 = 0; k0 < K; k0 += 16) {
        #pragma unroll
        for (int p = 0; p < 4; ++p) {
            int e = tid + p * 256;
            int r = e >> 4, cc = e & 15;
            int m = bm + r, k = k0 + cc;
            float v = (m < M && k < K) ? A[(long)m * K + k] : 0.f;
            As[cc][r] = v;
        }
        #pragma unroll
        for (int p = 0; p < 4; ++p) {
            int e = tid + p * 256;
            int r = e >> 6, cc = e & 63;
            int k = k0 + r, n = bn + cc;
            float v = (k < K && n < N) ? B[(long)k * N + n] : 0.f;
            Bs[r][cc] = v;
        }
        __syncthreads();
        #pragma unroll
        for (int kk = 0; kk < 16; ++kk) {
            float a[4], b[4];
            #pragma unroll
            for (int i = 0; i < 4; ++i) a[i] = As[kk][ty * 4 + i];
            #pragma unroll
            for (int j = 0; j < 4; ++j) b[j] = Bs[kk][tx * 4 + j];
            #pragma unroll
            for (int i = 0; i < 4; ++i)
                #pragma unroll
                for (int j = 0; j < 4; ++j)
                    acc[i][j] += a[i] * b[j];
        }
        __syncthreads();
    }
    #pragma unroll
    for (int i = 0; i < 4; ++i) {
        int m = bm + ty * 4 + i;
        if (m >= M) continue;
        #pragma unroll
        for (int j = 0; j < 4; ++j) {
            int n = bn + tx * 4 + j;
            if (n < N) {
                int pn = (n % 100) * 4 + (n / 100);   // unit-major permute
                C[(long)m * N + pn] = acc[i][j] + bias[n];
            }
        }
    }
}

// ---------------------------------------------------------------------------
// Recurrent role (R8 "X1"): 128 threads / 2 waves.  Thread u (<100) owns
// unit u completely: all 4 gate columns over full k=100, U in 400 VGPRs.
// Per step: 25 ds_read_b128 per wave (50 total), ZERO shfls, gates fully
// thread-local, 1 LDS-only barrier.  R7 probes showed the ds pipe
// (reads + shfls, ~12-25cyc each) was the step bottleneck.
// xz layout is unit-major float4 (i,f,g,o per unit).
// ---------------------------------------------------------------------------
__device__ void rec_role(
    const float* __restrict__ xz, int xz_ring,   // [T][400] or ring, permuted
    const float* __restrict__ U,                 // [100][400] original layout
    float* __restrict__ hout, int h_ring,        // [T][100] or ring [RN][100]
    int* flag_up, int* done_self, int* done_down, int* flag_self,
    float* lds)                                   // >= 256 floats
{
    float* hb0 = lds;          // 100 floats
    float* hb1 = lds + 128;    // 512B offset, 16B-aligned
    const int tid = threadIdx.x;
    const bool active = tid < NU;
    const int u = tid;

    float4 uf[NU];   // uf[k] = U[k][{0,100,200,300}+u]
    if (active) {
        #pragma unroll
        for (int k = 0; k < NU; ++k)
            uf[k] = make_float4(U[(long)k * NG + u],
                                U[(long)k * NG + NU + u],
                                U[(long)k * NG + 2 * NU + u],
                                U[(long)k * NG + 3 * NU + u]);
    }
    if (active) { hb0[u] = 0.f; hb1[u] = 0.f; }
    float c_state = 0.f;
    float4 xw0 = make_float4(0.f, 0.f, 0.f, 0.f), xw1 = xw0;
    __syncthreads();

    auto step = [&](const float* hrd, float* hwr, int t) {
        if (active) {
            const float4* h4 = (const float4*)hrd;
            float zx = xw0.x, zy = xw0.y, zz = xw0.z, zw = xw0.w;
            #pragma unroll
            for (int q = 0; q < 25; ++q) {
                float4 hv = h4[q];
                float hvals[4] = {hv.x, hv.y, hv.z, hv.w};
                #pragma unroll
                for (int j = 0; j < 4; ++j) {
                    float4 uv = uf[4 * q + j];
                    float hh = hvals[j];
                    zx += uv.x * hh;
                    zy += uv.y * hh;
                    zz += uv.z * hh;
                    zw += uv.w * hh;
                }
            }
            xw0 = xw1;
            int tp = t + 2;
            if (tp < T_STEPS) {
                long rr = xz_ring ? (long)(tp % RN) : (long)tp;
                xw1 = *(const float4*)&xz[rr * NG + 4 * u];
            }
            float iv = sigmoid_(zx);
            float fv = sigmoid_(zy);
            float gv = tanh_(zz);
            float ov = sigmoid_(zw);
            c_state = fv * c_state + iv * gv;
            float h = ov * tanh_(c_state);
            hwr[u] = h;
            long orow = h_ring ? (long)(t % RN) : (long)t;
            hout[orow * NU + u] = h;     // raw h; BN folded downstream
        }
        BARRIER_LDS();
    };

    for (int c = 0; c < NCHUNK; ++c) {
        if (flag_up) {
            int tgt = c + 2; if (tgt > NCHUNK) tgt = NCHUNK;
            wg_wait_ge(flag_up, tgt);
        }
        if (done_down && c >= RING) wg_wait_ge(done_down, c - RING + 1);
        if (c == 0 && active) {
            xw0 = *(const float4*)&xz[4 * u];
            xw1 = *(const float4*)&xz[NG + 4 * u];
        }
        const int t0 = c * CHUNK;
        for (int tt = 0; tt < CHUNK; tt += 2) {
            step(hb0, hb1, t0 + tt);
            step(hb1, hb0, t0 + tt + 1);
        }
        wg_publish(done_self, c + 1, flag_self, c + 1);
    }
}

// ---------------------------------------------------------------------------
// Projection role (R8): 128 threads / 2 waves, thread u computes all 4 gate
// columns of unit u (no butterfly), writes one coalesced float4 per row in
// the unit-major layout the rec role reads.  Upstream BN folded into wf/bc.
// ---------------------------------------------------------------------------
__device__ void proj_role(
    const float* __restrict__ hin,     // ring [RN][100] raw h
    const float* __restrict__ W,       // [100][400] original layout
    const float* __restrict__ bias,    // [400] original gate-major index
    const float* __restrict__ g, const float* __restrict__ be,
    const float* __restrict__ m, const float* __restrict__ v,
    float* __restrict__ xzout,         // ring [RN][400] permuted
    int* flag_up, int* done_self, int* done_down, int* flag_self,
    float* lds)                         // CHUNK*NU floats (48 KB)
{
    const int tid = threadIdx.x;
    const bool active = tid < NU;
    const int u = tid;

    float4 wf[NU];
    float4 bc = make_float4(0.f, 0.f, 0.f, 0.f);
    if (active) {
        bc = make_float4(bias[u], bias[NU + u], bias[2 * NU + u], bias[3 * NU + u]);
        #pragma unroll
        for (int k = 0; k < NU; ++k) {
            float sc = g[k] * rsqrtf(v[k] + 1e-3f);
            float sh = be[k] - m[k] * sc;
            float w0 = W[(long)k * NG + u];
            float w1 = W[(long)k * NG + NU + u];
            float w2 = W[(long)k * NG + 2 * NU + u];
            float w3 = W[(long)k * NG + 3 * NU + u];
            wf[k] = make_float4(sc * w0, sc * w1, sc * w2, sc * w3);
            bc.x += sh * w0;
            bc.y += sh * w1;
            bc.z += sh * w2;
            bc.w += sh * w3;
        }
    }

    for (int c = 0; c < NCHUNK; ++c) {
        wg_wait_ge(flag_up, c + 1);
        if (c >= RING) wg_wait_ge(done_down, c - RING + 1);
        // stage h chunk into LDS (flat float4 copy: 120*100 floats, 100%4==0)
        {
            const float4* src = (const float4*)(hin + (size_t)(c % RING) * CHUNK * NU);
            float4* dst = (float4*)lds;
            for (int i = tid; i < CHUNK * NU / 4; i += 128) dst[i] = src[i];
        }
        wg_publish(done_self, c + 1, (int*)0, 0);   // h slot free (syncthreads inside)
        if (active) {
            float* ob = xzout + (size_t)(c % RING) * CHUNK * NG;
            for (int r = 0; r < CHUNK; ++r) {
                const float4* h4 = (const float4*)(lds + r * NU);
                float zx = bc.x, zy = bc.y, zz = bc.z, zw = bc.w;
                #pragma unroll
                for (int q = 0; q < 25; ++q) {
                    float4 hv = h4[q];
                    float hvals[4] = {hv.x, hv.y, hv.z, hv.w};
                    #pragma unroll
                    for (int j = 0; j < 4; ++j) {
                        float4 wv = wf[4 * q + j];
                        float hh = hvals[j];
                        zx += wv.x * hh;
                        zy += wv.y * hh;
                        zz += wv.z * hh;
                        zw += wv.w * hh;
                    }
                }
                *(float4*)&ob[(long)r * NG + 4 * u] = make_float4(zx, zy, zz, zw);
            }
        }
        wg_publish(flag_self, c + 1, (int*)0, 0);   // xz chunk visible
    }
}

// ---------------------------------------------------------------------------
// Persistent pipeline: block 0..4 = rec1, proj2, rec2, proj3, rec3.
// 128 threads per block; __launch_bounds__(128,1) -> full 512-VGPR budget
// for the 400-float U/W register files.
// ---------------------------------------------------------------------------
__global__ __launch_bounds__(128, 1) void lstm_pipe_kernel(
    const float* xw1, const float* U1,
    const float* U2, const float* W2, const float* b2,
    const float* U3, const float* W3, const float* b3,
    const float* g1, const float* be1, const float* m1, const float* v1,
    const float* g2, const float* be2, const float* m2, const float* v2,
    float* h1r, float* h2r, float* xz2r, float* xz3r, float* h3,
    int* f)
{
    extern __shared__ float smem[];
    int* f_h1  = f +   0;
    int* d_p2  = f +  32;
    int* f_xz2 = f +  64;
    int* d_r2  = f +  96;
    int* f_h2  = f + 128;
    int* d_p3  = f + 160;
    int* f_xz3 = f + 192;
    int* d_r3  = f + 224;

    switch (blockIdx.x) {
    case 0: rec_role(xw1, 0, U1, h1r, 1, (int*)0, (int*)0, d_p2, f_h1, smem); break;
    case 1: proj_role(h1r, W2, b2, g1, be1, m1, v1, xz2r, f_h1, d_p2, d_r2, f_xz2, smem); break;
    case 2: rec_role(xz2r, 1, U2, h2r, 1, f_xz2, d_r2, d_p3, f_h2, smem); break;
    case 3: proj_role(h2r, W3, b3, g2, be2, m2, v2, xz3r, f_h2, d_p3, d_r3, f_xz3, smem); break;
    case 4: rec_role(xz3r, 1, U3, h3, 0, f_xz3, d_r3, (int*)0, (int*)0, smem); break;
    }
}

// ---------------------------------------------------------------------------
// Dense (100->3) + softmax, with BN3 folded into Wd/bd.
// ---------------------------------------------------------------------------
__global__ __launch_bounds__(256) void dense_softmax_kernel(
    const float* __restrict__ H,
    const float* __restrict__ Wd,
    const float* __restrict__ bd,
    const float* __restrict__ g3, const float* __restrict__ be3,
    const float* __restrict__ m3, const float* __restrict__ v3,
    float* __restrict__ out, int T)
{
    __shared__ float w[300];
    __shared__ float b[3];
    const int tid = threadIdx.x;
    for (int i = tid; i < 300; i += 256) {
        int k = i / 3;
        float sc = g3[k] * rsqrtf(v3[k] + 1e-3f);
        w[i] = Wd[i] * sc;
    }
    if (tid < 3) {
        float acc = bd[tid];
        for (int k = 0; k < NU; ++k) {
            float sc = g3[k] * rsqrtf(v3[k] + 1e-3f);
            float sh = be3[k] - m3[k] * sc;
            acc += sh * Wd[3 * k + tid];
        }
        b[tid] = acc;
    }
    __syncthreads();

    int row = blockIdx.x * blockDim.x + tid;
    if (row >= T) return;
    const float* h = H + (long)row * NU;
    float s0 = b[0], s1 = b[1], s2 = b[2];
    #pragma unroll 4
    for (int k = 0; k < NU; ++k) {
        float hv = h[k];
        s0 += hv * w[3 * k + 0];
        s1 += hv * w[3 * k + 1];
        s2 += hv * w[3 * k + 2];
    }
    float mx = fmaxf(s0, fmaxf(s1, s2));
    float e0 = __expf(s0 - mx), e1 = __expf(s1 - mx), e2 = __expf(s2 - mx);
    float inv = 1.f / (e0 + e1 + e2);
    out[(long)row * 3 + 0] = e0 * inv;
    out[(long)row * 3 + 1] = e1 * inv;
    out[(long)row * 3 + 2] = e2 * inv;
}

// ---------------------------------------------------------------------------
extern "C" void kernel_launch(void* const* d_in, const int* in_sizes, int n_in,
                              void* d_out, int out_size, void* d_ws, size_t ws_size,
                              hipStream_t stream)
{
    const float* x   = (const float*)d_in[0];
    const float* W1  = (const float*)d_in[1];
    const float* U1  = (const float*)d_in[2];
    const float* b1  = (const float*)d_in[3];
    const float* ga1 = (const float*)d_in[4];
    const float* be1 = (const float*)d_in[5];
    const float* mu1 = (const float*)d_in[6];
    const float* va1 = (const float*)d_in[7];
    const float* W2  = (const float*)d_in[8];
    const float* U2  = (const float*)d_in[9];
    const float* b2  = (const float*)d_in[10];
    const float* ga2 = (const float*)d_in[11];
    const float* be2 = (const float*)d_in[12];
    const float* mu2 = (const float*)d_in[13];
    const float* va2 = (const float*)d_in[14];
    const float* W3  = (const float*)d_in[15];
    const float* U3  = (const float*)d_in[16];
    const float* b3  = (const float*)d_in[17];
    const float* ga3 = (const float*)d_in[18];
    const float* be3 = (const float*)d_in[19];
    const float* mu3 = (const float*)d_in[20];
    const float* va3 = (const float*)d_in[21];
    const float* Wd  = (const float*)d_in[22];
    const float* bd  = (const float*)d_in[23];

    // workspace layout (floats) — total ~51.9 MB
    float* xw1  = (float*)d_ws;                       // T*400 (permuted)
    float* h3   = xw1  + (size_t)T_STEPS * NG;        // T*100 raw
    float* h1r  = h3   + (size_t)T_STEPS * NU;        // RN*100
    float* h2r  = h1r  + (size_t)RN * NU;
    float* xz2r = h2r  + (size_t)RN * NU;             // RN*400 (permuted)
    float* xz3r = xz2r + (size_t)RN * NG;
    int*   flags = (int*)(xz3r + (size_t)RN * NG);    // 512 ints
    float* out = (float*)d_out;

    dim3 blk(256);
    dim3 grd((NG + 63) / 64, (T_STEPS + 63) / 64);

    // 1) input projection of layer 1 (permuted-column output)
    gemm_bias_kernel<<<grd, blk, 0, stream>>>(x, W1, b1, xw1, T_STEPS, NG, DIN);
    // 2) zero the pipeline flags
    hipMemsetAsync(flags, 0, 512 * sizeof(int), stream);
    // 3) persistent pipeline: 5 blocks x 128 threads, 48 KB dynamic LDS
    lstm_pipe_kernel<<<5, 128, CHUNK * NU * sizeof(float), stream>>>(
        xw1, U1, U2, W2, b2, U3, W3, b3,
        ga1, be1, mu1, va1, ga2, be2, mu2, va2,
        h1r, h2r, xz2r, xz3r, h3, flags);
    // 4) dense + softmax (BN3 folded)
    dense_softmax_kernel<<<(T_STEPS + 255) / 256, 256, 0, stream>>>(
        h3, Wd, bd, ga3, be3, mu3, va3, out, T_STEPS);
}

// Round 9
// 20727.324 us; speedup vs baseline: 10.2362x; 10.2362x over previous
//
#include <hip/hip_runtime.h>

#define T_STEPS 24000
#define DIN 598
#define NU 100      // hidden units
#define NG 400      // 4 * NU gates
#define KHALF 52    // k-slice per thread (2 x 52 = 104 = padded K)
#define KPAD 104
#define CHUNK 120   // steps per pipeline chunk
#define NCHUNK 200
#define RING 8      // ring capacity in chunks
#define RN (RING * CHUNK)   // 960 ring rows

// LDS-only barrier: orders ds ops without draining global loads/stores.
#define BARRIER_LDS() asm volatile("s_waitcnt lgkmcnt(0)\n\ts_barrier" ::: "memory")

// ---------------------------------------------------------------------------
// cross-WG sync helpers (device-scope; per-XCD L2s are non-coherent)
// ---------------------------------------------------------------------------
__device__ __forceinline__ void wg_wait_ge(int* flag, int target) {
    if (threadIdx.x == 0) {
        while (__hip_atomic_load(flag, __ATOMIC_RELAXED, __HIP_MEMORY_SCOPE_AGENT) < target)
            __builtin_amdgcn_s_sleep(2);
    }
    __syncthreads();
    __builtin_amdgcn_fence(__ATOMIC_ACQUIRE, "agent");
}
__device__ __forceinline__ void wg_publish(int* a, int va, int* b, int vb) {
    __syncthreads();
    if (threadIdx.x == 0) {
        if (a) __hip_atomic_store(a, va, __ATOMIC_RELEASE, __HIP_MEMORY_SCOPE_AGENT);
        if (b) __hip_atomic_store(b, vb, __ATOMIC_RELEASE, __HIP_MEMORY_SCOPE_AGENT);
    }
}

// ---------------------------------------------------------------------------
__device__ __forceinline__ float sigmoid_(float x) {
    return 1.f / (1.f + __expf(-x));
}
__device__ __forceinline__ float tanh_(float x) {
    float e = __expf(2.f * x);
    return 1.f - 2.f / (e + 1.f);
}

// ---------------------------------------------------------------------------
// GEMM with bias: C[M,N] = A[M,K] @ B[K,N] + bias[N]   (fp32, 64x64 tile)
// Writes PERMUTED columns: col n=(g*100+u) lands at u*4+g (unit-major i,f,g,o)
// so the rec role reads one coalesced float2 per thread per step.
// ---------------------------------------------------------------------------
__global__ __launch_bounds__(256) void gemm_bias_kernel(
    const float* __restrict__ A, const float* __restrict__ B,
    const float* __restrict__ bias, float* __restrict__ C,
    int M, int N, int K)
{
    __shared__ float As[16][65];
    __shared__ float Bs[16][65];
    const int tid = threadIdx.x;
    const int tx = tid & 15;
    const int ty = tid >> 4;
    const int bm = blockIdx.y * 64;
    const int bn = blockIdx.x * 64;
    float acc[4][4] = {};

    for (int k0 = 0; k0 < K; k0 += 16) {
        #pragma unroll
        for (int p = 0; p < 4; ++p) {
            int e = tid + p * 256;
            int r = e >> 4, cc = e & 15;
            int m = bm + r, k = k0 + cc;
            float v = (m < M && k < K) ? A[(long)m * K + k] : 0.f;
            As[cc][r] = v;
        }
        #pragma unroll
        for (int p = 0; p < 4; ++p) {
            int e = tid + p * 256;
            int r = e >> 6, cc = e & 63;
            int k = k0 + r, n = bn + cc;
            float v = (k < K && n < N) ? B[(long)k * N + n] : 0.f;
            Bs[r][cc] = v;
        }
        __syncthreads();
        #pragma unroll
        for (int kk = 0; kk < 16; ++kk) {
            float a[4], b[4];
            #pragma unroll
            for (int i = 0; i < 4; ++i) a[i] = As[kk][ty * 4 + i];
            #pragma unroll
            for (int j = 0; j < 4; ++j) b[j] = Bs[kk][tx * 4 + j];
            #pragma unroll
            for (int i = 0; i < 4; ++i)
                #pragma unroll
                for (int j = 0; j < 4; ++j)
                    acc[i][j] += a[i] * b[j];
        }
        __syncthreads();
    }
    #pragma unroll
    for (int i = 0; i < 4; ++i) {
        int m = bm + ty * 4 + i;
        if (m >= M) continue;
        #pragma unroll
        for (int j = 0; j < 4; ++j) {
            int n = bn + tx * 4 + j;
            if (n < N) {
                int pn = (n % 100) * 4 + (n / 100);   // unit-major permute
                C[(long)m * N + pn] = acc[i][j] + bias[n];
            }
        }
    }
}

// ---------------------------------------------------------------------------
// Recurrent role (R9): 256 threads / 4 waves.  Thread 2u+s owns ALL FOUR
// gate columns of unit u over k-half [52s, 52s+52) (K padded to 104).
// Weights: 52 float4 = 208 VGPRs (fits the 256 addressable-VGPR wall that
// killed R8).  Per step: 13 ds_read_b128 + 4 shfl_xor(1) per wave
// (~72 ds-instrs/CU vs R5's ~105), partner is always in-wave, redundant
// c/h per pair, 1 LDS-only barrier.  xz is unit-major -> float2 xw load.
// ---------------------------------------------------------------------------
__device__ void rec_role(
    const float* __restrict__ xz, int xz_ring,   // [T][400] or ring, permuted
    const float* __restrict__ U,                 // [100][400] original layout
    float* __restrict__ hout, int h_ring,        // [T][100] or ring [RN][100]
    int* flag_up, int* done_self, int* done_down, int* flag_self,
    float* lds)                                   // >= 2*KPAD floats
{
    float* hb0 = lds;            // 104 floats (pad zeros)
    float* hb1 = lds + KPAD;     // 416 B offset, 16B-aligned
    const int tid = threadIdx.x;
    const bool active = tid < 2 * NU;   // 200 workers
    const int u = tid >> 1;
    const int s = tid & 1;

    // uf[i] = U[k][{0,100,200,300}+u] for k = 52s+i; zeros for k >= 100
    float4 uf[KHALF];
    if (active) {
        const int k0 = KHALF * s;
        #pragma unroll
        for (int i = 0; i < KHALF; ++i) {
            int k = k0 + i;
            uf[i] = (k < NU)
                ? make_float4(U[(long)k * NG + u],       U[(long)k * NG + NU + u],
                              U[(long)k * NG + 2 * NU + u], U[(long)k * NG + 3 * NU + u])
                : make_float4(0.f, 0.f, 0.f, 0.f);
        }
    }
    if (tid < KPAD) { hb0[tid] = 0.f; hb1[tid] = 0.f; }
    float c_state = 0.f;
    float2 xw0 = make_float2(0.f, 0.f), xw1 = xw0;
    __syncthreads();

    auto step = [&](const float* hrd, float* hwr, int t) {
        if (active) {
            const float4* h4 = (const float4*)(hrd + KHALF * s);
            float ax = 0.f, ay = 0.f, az = 0.f, aw = 0.f;
            #pragma unroll
            for (int q = 0; q < 13; ++q) {
                float4 hv = h4[q];
                float hh[4] = {hv.x, hv.y, hv.z, hv.w};
                #pragma unroll
                for (int j = 0; j < 4; ++j) {
                    float4 uv = uf[4 * q + j];
                    ax += uv.x * hh[j];
                    ay += uv.y * hh[j];
                    az += uv.z * hh[j];
                    aw += uv.w * hh[j];
                }
            }
            // fold this thread's xw pair: s=0 -> (i,f), s=1 -> (g,o)
            if (s == 0) { ax += xw0.x; ay += xw0.y; }
            else        { az += xw0.x; aw += xw0.y; }
            xw0 = xw1;
            int tp = t + 2;
            if (tp < T_STEPS) {
                long rr = xz_ring ? (long)(tp % RN) : (long)tp;
                xw1 = *(const float2*)&xz[rr * NG + 4 * u + 2 * s];
            }
            // combine k-halves with in-wave partner (tid^1)
            ax += __shfl_xor(ax, 1);
            ay += __shfl_xor(ay, 1);
            az += __shfl_xor(az, 1);
            aw += __shfl_xor(aw, 1);
            float iv = sigmoid_(ax);
            float fv = sigmoid_(ay);
            float gv = tanh_(az);
            float ov = sigmoid_(aw);
            c_state = fv * c_state + iv * gv;    // replicated per pair
            float h = ov * tanh_(c_state);
            if (s == 0) {
                hwr[u] = h;                       // pad [100..103] stays 0
                long orow = h_ring ? (long)(t % RN) : (long)t;
                hout[orow * NU + u] = h;          // raw h; BN folded downstream
            }
        }
        BARRIER_LDS();
    };

    for (int c = 0; c < NCHUNK; ++c) {
        if (flag_up) {
            int tgt = c + 2; if (tgt > NCHUNK) tgt = NCHUNK;
            wg_wait_ge(flag_up, tgt);
        }
        if (done_down && c >= RING) wg_wait_ge(done_down, c - RING + 1);
        if (c == 0 && active) {
            xw0 = *(const float2*)&xz[4 * u + 2 * s];
            xw1 = *(const float2*)&xz[NG + 4 * u + 2 * s];
        }
        const int t0 = c * CHUNK;
        for (int tt = 0; tt < CHUNK; tt += 2) {
            step(hb0, hb1, t0 + tt);
            step(hb1, hb0, t0 + tt + 1);
        }
        wg_publish(done_self, c + 1, flag_self, c + 1);
    }
}

// ---------------------------------------------------------------------------
// Projection role (R9): same S=2 layout as rec.  Thread 2u+s computes 4 gate
// partials of unit u over its k-half for each row, combines with in-wave
// partner, writes its float2 in the unit-major layout.  BN folded.
// ---------------------------------------------------------------------------
__device__ void proj_role(
    const float* __restrict__ hin,     // ring [RN][100] raw h
    const float* __restrict__ W,       // [100][400] original layout
    const float* __restrict__ bias,    // [400] gate-major index
    const float* __restrict__ g, const float* __restrict__ be,
    const float* __restrict__ m, const float* __restrict__ v,
    float* __restrict__ xzout,         // ring [RN][400] permuted
    int* flag_up, int* done_self, int* done_down, int* flag_self,
    float* lds)                         // CHUNK*KPAD floats (49.9 KB)
{
    const int tid = threadIdx.x;
    const bool active = tid < 2 * NU;
    const int u = tid >> 1;
    const int s = tid & 1;

    float4 wf[KHALF];
    float bx = 0.f, by = 0.f;     // this thread's output-pair bias (after fold)
    if (active) {
        const int k0 = KHALF * s;
        float pbx = 0.f, pby = 0.f, pbz = 0.f, pbw = 0.f;
        #pragma unroll
        for (int i = 0; i < KHALF; ++i) {
            int k = k0 + i;
            if (k < NU) {
                float sc = g[k] * rsqrtf(v[k] + 1e-3f);
                float sh = be[k] - m[k] * sc;
                float w0 = W[(long)k * NG + u];
                float w1 = W[(long)k * NG + NU + u];
                float w2 = W[(long)k * NG + 2 * NU + u];
                float w3 = W[(long)k * NG + 3 * NU + u];
                wf[i] = make_float4(sc * w0, sc * w1, sc * w2, sc * w3);
                pbx += sh * w0; pby += sh * w1; pbz += sh * w2; pbw += sh * w3;
            } else {
                wf[i] = make_float4(0.f, 0.f, 0.f, 0.f);
            }
        }
        pbx += __shfl_xor(pbx, 1); pby += __shfl_xor(pby, 1);
        pbz += __shfl_xor(pbz, 1); pbw += __shfl_xor(pbw, 1);
        if (s == 0) { bx = bias[u]          + pbx; by = bias[NU + u]     + pby; }
        else        { bx = bias[2 * NU + u] + pbz; by = bias[3 * NU + u] + pbw; }
    }

    for (int c = 0; c < NCHUNK; ++c) {
        wg_wait_ge(flag_up, c + 1);
        if (c >= RING) wg_wait_ge(done_down, c - RING + 1);
        // stage h chunk into LDS, row stride KPAD (zeros in pad)
        const float* src = hin + (size_t)(c % RING) * CHUNK * NU;
        for (int idx = tid; idx < CHUNK * KPAD; idx += 256) {
            int r = idx / KPAD, k = idx - r * KPAD;
            lds[idx] = (k < NU) ? src[r * NU + k] : 0.f;
        }
        wg_publish(done_self, c + 1, (int*)0, 0);   // h slot free (syncthreads inside)
        if (active) {
            float* ob = xzout + (size_t)(c % RING) * CHUNK * NG;
            for (int r = 0; r < CHUNK; ++r) {
                const float4* h4 = (const float4*)(lds + r * KPAD + KHALF * s);
                float ax = 0.f, ay = 0.f, az = 0.f, aw = 0.f;
                #pragma unroll
                for (int q = 0; q < 13; ++q) {
                    float4 hv = h4[q];
                    float hh[4] = {hv.x, hv.y, hv.z, hv.w};
                    #pragma unroll
                    for (int j = 0; j < 4; ++j) {
                        float4 wv = wf[4 * q + j];
                        ax += wv.x * hh[j];
                        ay += wv.y * hh[j];
                        az += wv.z * hh[j];
                        aw += wv.w * hh[j];
                    }
                }
                ax += __shfl_xor(ax, 1);
                ay += __shfl_xor(ay, 1);
                az += __shfl_xor(az, 1);
                aw += __shfl_xor(aw, 1);
                float2 o2 = (s == 0) ? make_float2(ax + bx, ay + by)
                                     : make_float2(az + bx, aw + by);
                *(float2*)&ob[(long)r * NG + 4 * u + 2 * s] = o2;
            }
        }
        wg_publish(flag_self, c + 1, (int*)0, 0);   // xz chunk visible
    }
}

// ---------------------------------------------------------------------------
// Persistent pipeline: block 0..4 = rec1, proj2, rec2, proj3, rec3.
// 256 threads; __launch_bounds__(256,1): 4 waves, 1 wave/SIMD, full register
// headroom for the 208-float weight files (overflow -> AGPR, not scratch).
// ---------------------------------------------------------------------------
__global__ __launch_bounds__(256, 1) void lstm_pipe_kernel(
    const float* xw1, const float* U1,
    const float* U2, const float* W2, const float* b2,
    const float* U3, const float* W3, const float* b3,
    const float* g1, const float* be1, const float* m1, const float* v1,
    const float* g2, const float* be2, const float* m2, const float* v2,
    float* h1r, float* h2r, float* xz2r, float* xz3r, float* h3,
    int* f)
{
    extern __shared__ float smem[];
    int* f_h1  = f +   0;
    int* d_p2  = f +  32;
    int* f_xz2 = f +  64;
    int* d_r2  = f +  96;
    int* f_h2  = f + 128;
    int* d_p3  = f + 160;
    int* f_xz3 = f + 192;
    int* d_r3  = f + 224;

    switch (blockIdx.x) {
    case 0: rec_role(xw1, 0, U1, h1r, 1, (int*)0, (int*)0, d_p2, f_h1, smem); break;
    case 1: proj_role(h1r, W2, b2, g1, be1, m1, v1, xz2r, f_h1, d_p2, d_r2, f_xz2, smem); break;
    case 2: rec_role(xz2r, 1, U2, h2r, 1, f_xz2, d_r2, d_p3, f_h2, smem); break;
    case 3: proj_role(h2r, W3, b3, g2, be2, m2, v2, xz3r, f_h2, d_p3, d_r3, f_xz3, smem); break;
    case 4: rec_role(xz3r, 1, U3, h3, 0, f_xz3, d_r3, (int*)0, (int*)0, smem); break;
    }
}

// ---------------------------------------------------------------------------
// Dense (100->3) + softmax, with BN3 folded into Wd/bd.
// ---------------------------------------------------------------------------
__global__ __launch_bounds__(256) void dense_softmax_kernel(
    const float* __restrict__ H,
    const float* __restrict__ Wd,
    const float* __restrict__ bd,
    const float* __restrict__ g3, const float* __restrict__ be3,
    const float* __restrict__ m3, const float* __restrict__ v3,
    float* __restrict__ out, int T)
{
    __shared__ float w[300];
    __shared__ float b[3];
    const int tid = threadIdx.x;
    for (int i = tid; i < 300; i += 256) {
        int k = i / 3;
        float sc = g3[k] * rsqrtf(v3[k] + 1e-3f);
        w[i] = Wd[i] * sc;
    }
    if (tid < 3) {
        float acc = bd[tid];
        for (int k = 0; k < NU; ++k) {
            float sc = g3[k] * rsqrtf(v3[k] + 1e-3f);
            float sh = be3[k] - m3[k] * sc;
            acc += sh * Wd[3 * k + tid];
        }
        b[tid] = acc;
    }
    __syncthreads();

    int row = blockIdx.x * blockDim.x + tid;
    if (row >= T) return;
    const float* h = H + (long)row * NU;
    float s0 = b[0], s1 = b[1], s2 = b[2];
    #pragma unroll 4
    for (int k = 0; k < NU; ++k) {
        float hv = h[k];
        s0 += hv * w[3 * k + 0];
        s1 += hv * w[3 * k + 1];
        s2 += hv * w[3 * k + 2];
    }
    float mx = fmaxf(s0, fmaxf(s1, s2));
    float e0 = __expf(s0 - mx), e1 = __expf(s1 - mx), e2 = __expf(s2 - mx);
    float inv = 1.f / (e0 + e1 + e2);
    out[(long)row * 3 + 0] = e0 * inv;
    out[(long)row * 3 + 1] = e1 * inv;
    out[(long)row * 3 + 2] = e2 * inv;
}

// ---------------------------------------------------------------------------
extern "C" void kernel_launch(void* const* d_in, const int* in_sizes, int n_in,
                              void* d_out, int out_size, void* d_ws, size_t ws_size,
                              hipStream_t stream)
{
    const float* x   = (const float*)d_in[0];
    const float* W1  = (const float*)d_in[1];
    const float* U1  = (const float*)d_in[2];
    const float* b1  = (const float*)d_in[3];
    const float* ga1 = (const float*)d_in[4];
    const float* be1 = (const float*)d_in[5];
    const float* mu1 = (const float*)d_in[6];
    const float* va1 = (const float*)d_in[7];
    const float* W2  = (const float*)d_in[8];
    const float* U2  = (const float*)d_in[9];
    const float* b2  = (const float*)d_in[10];
    const float* ga2 = (const float*)d_in[11];
    const float* be2 = (const float*)d_in[12];
    const float* mu2 = (const float*)d_in[13];
    const float* va2 = (const float*)d_in[14];
    const float* W3  = (const float*)d_in[15];
    const float* U3  = (const float*)d_in[16];
    const float* b3  = (const float*)d_in[17];
    const float* ga3 = (const float*)d_in[18];
    const float* be3 = (const float*)d_in[19];
    const float* mu3 = (const float*)d_in[20];
    const float* va3 = (const float*)d_in[21];
    const float* Wd  = (const float*)d_in[22];
    const float* bd  = (const float*)d_in[23];

    // workspace layout (floats) — total ~51.9 MB
    float* xw1  = (float*)d_ws;                       // T*400 (permuted)
    float* h3   = xw1  + (size_t)T_STEPS * NG;        // T*100 raw
    float* h1r  = h3   + (size_t)T_STEPS * NU;        // RN*100
    float* h2r  = h1r  + (size_t)RN * NU;
    float* xz2r = h2r  + (size_t)RN * NU;             // RN*400 (permuted)
    float* xz3r = xz2r + (size_t)RN * NG;
    int*   flags = (int*)(xz3r + (size_t)RN * NG);    // 512 ints
    float* out = (float*)d_out;

    dim3 blk(256);
    dim3 grd((NG + 63) / 64, (T_STEPS + 63) / 64);

    // 1) input projection of layer 1 (permuted-column output)
    gemm_bias_kernel<<<grd, blk, 0, stream>>>(x, W1, b1, xw1, T_STEPS, NG, DIN);
    // 2) zero the pipeline flags
    hipMemsetAsync(flags, 0, 512 * sizeof(int), stream);
    // 3) persistent pipeline: 5 blocks x 256 threads, 49.9 KB dynamic LDS
    lstm_pipe_kernel<<<5, 256, CHUNK * KPAD * sizeof(float), stream>>>(
        xw1, U1, U2, W2, b2, U3, W3, b3,
        ga1, be1, mu1, va1, ga2, be2, mu2, va2,
        h1r, h2r, xz2r, xz3r, h3, flags);
    // 4) dense + softmax (BN3 folded)
    dense_softmax_kernel<<<(T_STEPS + 255) / 256, 256, 0, stream>>>(
        h3, Wd, bd, ga3, be3, mu3, va3, out, T_STEPS);
}

// Round 11
// 18903.139 us; speedup vs baseline: 11.2240x; 1.0965x over previous
//
#include <hip/hip_runtime.h>

#define T_STEPS 24000
#define DIN 598
#define NU 100      // hidden units
#define NG 400      // 4 * NU gates
#define KHALF 52    // k-slice per thread (2 x 52 = 104 = padded K)
#define KPAD 104
#define CHUNK 240   // steps per pipeline chunk (R11: was 120; halves sync rounds)
#define NCHUNK 100
#define RING 4      // ring capacity in chunks (RN unchanged -> same memory)
#define RN (RING * CHUNK)   // 960 ring rows

// LDS-only barrier: orders ds ops without draining global loads/stores.
#define BARRIER_LDS() asm volatile("s_waitcnt lgkmcnt(0)\n\ts_barrier" ::: "memory")

// ---------------------------------------------------------------------------
// cross-WG sync helpers (device-scope; per-XCD L2s are non-coherent)
// ---------------------------------------------------------------------------
__device__ __forceinline__ void wg_wait_ge(int* flag, int target) {
    if (threadIdx.x == 0) {
        while (__hip_atomic_load(flag, __ATOMIC_RELAXED, __HIP_MEMORY_SCOPE_AGENT) < target)
            __builtin_amdgcn_s_sleep(2);
    }
    __syncthreads();
    __builtin_amdgcn_fence(__ATOMIC_ACQUIRE, "agent");
}
__device__ __forceinline__ void wg_publish(int* a, int va, int* b, int vb) {
    __syncthreads();
    if (threadIdx.x == 0) {
        if (a) __hip_atomic_store(a, va, __ATOMIC_RELEASE, __HIP_MEMORY_SCOPE_AGENT);
        if (b) __hip_atomic_store(b, vb, __ATOMIC_RELEASE, __HIP_MEMORY_SCOPE_AGENT);
    }
}

// ---------------------------------------------------------------------------
__device__ __forceinline__ float sigmoid_(float x) {
    return 1.f / (1.f + __expf(-x));
}
__device__ __forceinline__ float tanh_(float x) {
    float e = __expf(2.f * x);
    return 1.f - 2.f / (e + 1.f);
}

// ---------------------------------------------------------------------------
// GEMM with bias: C[M,N] = A[M,K] @ B[K,N] + bias[N]   (fp32, 64x64 tile)
// Writes PERMUTED columns: col n=(g*100+u) lands at u*4+g (unit-major i,f,g,o).
// ---------------------------------------------------------------------------
__global__ __launch_bounds__(256) void gemm_bias_kernel(
    const float* __restrict__ A, const float* __restrict__ B,
    const float* __restrict__ bias, float* __restrict__ C,
    int M, int N, int K)
{
    __shared__ float As[16][65];
    __shared__ float Bs[16][65];
    const int tid = threadIdx.x;
    const int tx = tid & 15;
    const int ty = tid >> 4;
    const int bm = blockIdx.y * 64;
    const int bn = blockIdx.x * 64;
    float acc[4][4] = {};

    for (int k0 = 0; k0 < K; k0 += 16) {
        #pragma unroll
        for (int p = 0; p < 4; ++p) {
            int e = tid + p * 256;
            int r = e >> 4, cc = e & 15;
            int m = bm + r, k = k0 + cc;
            float v = (m < M && k < K) ? A[(long)m * K + k] : 0.f;
            As[cc][r] = v;
        }
        #pragma unroll
        for (int p = 0; p < 4; ++p) {
            int e = tid + p * 256;
            int r = e >> 6, cc = e & 63;
            int k = k0 + r, n = bn + cc;
            float v = (k < K && n < N) ? B[(long)k * N + n] : 0.f;
            Bs[r][cc] = v;
        }
        __syncthreads();
        #pragma unroll
        for (int kk = 0; kk < 16; ++kk) {
            float a[4], b[4];
            #pragma unroll
            for (int i = 0; i < 4; ++i) a[i] = As[kk][ty * 4 + i];
            #pragma unroll
            for (int j = 0; j < 4; ++j) b[j] = Bs[kk][tx * 4 + j];
            #pragma unroll
            for (int i = 0; i < 4; ++i)
                #pragma unroll
                for (int j = 0; j < 4; ++j)
                    acc[i][j] += a[i] * b[j];
        }
        __syncthreads();
    }
    #pragma unroll
    for (int i = 0; i < 4; ++i) {
        int m = bm + ty * 4 + i;
        if (m >= M) continue;
        #pragma unroll
        for (int j = 0; j < 4; ++j) {
            int n = bn + tx * 4 + j;
            if (n < N) {
                int pn = (n % 100) * 4 + (n / 100);   // unit-major permute
                C[(long)m * N + pn] = acc[i][j] + bias[n];
            }
        }
    }
}

// ---------------------------------------------------------------------------
// Recurrent role (R11 = R9 + transposed/batched h store).  256 thr / 4 waves.
// Thread 2u+s owns unit u's 4 gates over k-half s (208 weight VGPRs).
// h output is TRANSPOSED: hout[u][t] (stride = h_stride), and thread u
// (s==0) buffers 4 steps in registers, issuing one global_store_dwordx4
// every 4th step -> 75% fewer stores on the serial chain.
// Per-step sync: hard s_barrier (LDS-only waitcnt) — R10's soft barrier was
// both slower and racy; do not revisit.
// ---------------------------------------------------------------------------
__device__ void rec_role(
    const float* __restrict__ xz, int xz_ring,   // [T][400] or ring, permuted
    const float* __restrict__ U,                 // [100][400] original layout
    float* __restrict__ hout, long h_stride, int h_ring, // transposed [100][h_stride]
    int* flag_up, int* done_self, int* done_down, int* flag_self,
    float* lds)                                   // >= 2*KPAD floats
{
    float* hb0 = lds;            // 104 floats (pad zeros)
    float* hb1 = lds + KPAD;     // 416 B offset, 16B-aligned
    const int tid = threadIdx.x;
    const bool active = tid < 2 * NU;   // 200 workers
    const int u = tid >> 1;
    const int s = tid & 1;

    // uf[i] = U[k][{0,100,200,300}+u] for k = 52s+i; zeros for k >= 100
    float4 uf[KHALF];
    if (active) {
        const int k0 = KHALF * s;
        #pragma unroll
        for (int i = 0; i < KHALF; ++i) {
            int k = k0 + i;
            uf[i] = (k < NU)
                ? make_float4(U[(long)k * NG + u],       U[(long)k * NG + NU + u],
                              U[(long)k * NG + 2 * NU + u], U[(long)k * NG + 3 * NU + u])
                : make_float4(0.f, 0.f, 0.f, 0.f);
        }
    }
    if (tid < KPAD) { hb0[tid] = 0.f; hb1[tid] = 0.f; }
    float c_state = 0.f;
    float2 xw0 = make_float2(0.f, 0.f), xw1 = xw0;
    float4 hbatch = make_float4(0.f, 0.f, 0.f, 0.f);
    __syncthreads();

    auto step = [&](const float* hrd, float* hwr, int t) {
        if (active) {
            const float4* h4 = (const float4*)(hrd + KHALF * s);
            float ax = 0.f, ay = 0.f, az = 0.f, aw = 0.f;
            #pragma unroll
            for (int q = 0; q < 13; ++q) {
                float4 hv = h4[q];
                float hh[4] = {hv.x, hv.y, hv.z, hv.w};
                #pragma unroll
                for (int j = 0; j < 4; ++j) {
                    float4 uv = uf[4 * q + j];
                    ax += uv.x * hh[j];
                    ay += uv.y * hh[j];
                    az += uv.z * hh[j];
                    aw += uv.w * hh[j];
                }
            }
            // fold this thread's xw pair: s=0 -> (i,f), s=1 -> (g,o)
            if (s == 0) { ax += xw0.x; ay += xw0.y; }
            else        { az += xw0.x; aw += xw0.y; }
            xw0 = xw1;
            int tp = t + 2;
            if (tp < T_STEPS) {
                long rr = xz_ring ? (long)(tp % RN) : (long)tp;
                xw1 = *(const float2*)&xz[rr * NG + 4 * u + 2 * s];
            }
            // combine k-halves with in-wave partner (tid^1)
            ax += __shfl_xor(ax, 1);
            ay += __shfl_xor(ay, 1);
            az += __shfl_xor(az, 1);
            aw += __shfl_xor(aw, 1);
            float iv = sigmoid_(ax);
            float fv = sigmoid_(ay);
            float gv = tanh_(az);
            float ov = sigmoid_(aw);
            c_state = fv * c_state + iv * gv;    // replicated per pair
            float h = ov * tanh_(c_state);
            if (s == 0) {
                hwr[u] = h;                       // pad [100..103] stays 0
                // batch 4 steps of h, flush with one dwordx4 (t%4==3)
                int ph = t & 3;
                if      (ph == 0) hbatch.x = h;
                else if (ph == 1) hbatch.y = h;
                else if (ph == 2) hbatch.z = h;
                else {
                    hbatch.w = h;
                    long tb = h_ring ? (long)((t - 3) % RN) : (long)(t - 3);
                    *(float4*)&hout[(long)u * h_stride + tb] = hbatch;
                }
            }
        }
        BARRIER_LDS();
    };

    for (int c = 0; c < NCHUNK; ++c) {
        if (flag_up) {
            int tgt = c + 2; if (tgt > NCHUNK) tgt = NCHUNK;
            wg_wait_ge(flag_up, tgt);
        }
        if (done_down && c >= RING) wg_wait_ge(done_down, c - RING + 1);
        if (c == 0 && active) {
            xw0 = *(const float2*)&xz[4 * u + 2 * s];
            xw1 = *(const float2*)&xz[NG + 4 * u + 2 * s];
        }
        const int t0 = c * CHUNK;
        for (int tt = 0; tt < CHUNK; tt += 2) {
            step(hb0, hb1, t0 + tt);
            step(hb1, hb0, t0 + tt + 1);
        }
        wg_publish(done_self, c + 1, flag_self, c + 1);   // vmcnt(0) drained inside
    }
}

// ---------------------------------------------------------------------------
// Projection role (R11): reads TRANSPOSED h ring hin[u][RN].  Staging loop
// iterates t-major so global reads stay coalesced.  Otherwise identical R9.
// ---------------------------------------------------------------------------
__device__ void proj_role(
    const float* __restrict__ hin,     // transposed ring [100][RN]
    const float* __restrict__ W,       // [100][400] original layout
    const float* __restrict__ bias,    // [400] gate-major index
    const float* __restrict__ g, const float* __restrict__ be,
    const float* __restrict__ m, const float* __restrict__ v,
    float* __restrict__ xzout,         // ring [RN][400] permuted
    int* flag_up, int* done_self, int* done_down, int* flag_self,
    float* lds)                         // CHUNK*KPAD floats (99.8 KB)
{
    const int tid = threadIdx.x;
    const bool active = tid < 2 * NU;
    const int u = tid >> 1;
    const int s = tid & 1;

    float4 wf[KHALF];
    float bx = 0.f, by = 0.f;
    if (active) {
        const int k0 = KHALF * s;
        float pbx = 0.f, pby = 0.f, pbz = 0.f, pbw = 0.f;
        #pragma unroll
        for (int i = 0; i < KHALF; ++i) {
            int k = k0 + i;
            if (k < NU) {
                float sc = g[k] * rsqrtf(v[k] + 1e-3f);
                float sh = be[k] - m[k] * sc;
                float w0 = W[(long)k * NG + u];
                float w1 = W[(long)k * NG + NU + u];
                float w2 = W[(long)k * NG + 2 * NU + u];
                float w3 = W[(long)k * NG + 3 * NU + u];
                wf[i] = make_float4(sc * w0, sc * w1, sc * w2, sc * w3);
                pbx += sh * w0; pby += sh * w1; pbz += sh * w2; pbw += sh * w3;
            } else {
                wf[i] = make_float4(0.f, 0.f, 0.f, 0.f);
            }
        }
        pbx += __shfl_xor(pbx, 1); pby += __shfl_xor(pby, 1);
        pbz += __shfl_xor(pbz, 1); pbw += __shfl_xor(pbw, 1);
        if (s == 0) { bx = bias[u]          + pbx; by = bias[NU + u]     + pby; }
        else        { bx = bias[2 * NU + u] + pbz; by = bias[3 * NU + u] + pbw; }
    }

    for (int c = 0; c < NCHUNK; ++c) {
        wg_wait_ge(flag_up, c + 1);
        if (c >= RING) wg_wait_ge(done_down, c - RING + 1);
        // stage h chunk into LDS[r][k] (row stride KPAD, zeros in pad).
        // t-major iteration: consecutive tid -> consecutive t (coalesced).
        {
            const int tbase = (c % RING) * CHUNK;   // == t0 % RN
            for (int idx = tid; idx < KPAD * CHUNK; idx += 256) {
                int k = idx / CHUNK, r = idx - k * CHUNK;
                lds[r * KPAD + k] = (k < NU) ? hin[(long)k * RN + tbase + r] : 0.f;
            }
        }
        wg_publish(done_self, c + 1, (int*)0, 0);
        if (active) {
            float* ob = xzout + (size_t)(c % RING) * CHUNK * NG;
            for (int r = 0; r < CHUNK; ++r) {
                const float4* h4 = (const float4*)(lds + r * KPAD + KHALF * s);
                float ax = 0.f, ay = 0.f, az = 0.f, aw = 0.f;
                #pragma unroll
                for (int q = 0; q < 13; ++q) {
                    float4 hv = h4[q];
                    float hh[4] = {hv.x, hv.y, hv.z, hv.w};
                    #pragma unroll
                    for (int j = 0; j < 4; ++j) {
                        float4 wv = wf[4 * q + j];
                        ax += wv.x * hh[j];
                        ay += wv.y * hh[j];
                        az += wv.z * hh[j];
                        aw += wv.w * hh[j];
                    }
                }
                ax += __shfl_xor(ax, 1);
                ay += __shfl_xor(ay, 1);
                az += __shfl_xor(az, 1);
                aw += __shfl_xor(aw, 1);
                float2 o2 = (s == 0) ? make_float2(ax + bx, ay + by)
                                     : make_float2(az + bx, aw + by);
                *(float2*)&ob[(long)r * NG + 4 * u + 2 * s] = o2;
            }
        }
        wg_publish(flag_self, c + 1, (int*)0, 0);
    }
}

// ---------------------------------------------------------------------------
// Persistent pipeline: block 0..4 = rec1, proj2, rec2, proj3, rec3.
// ---------------------------------------------------------------------------
__global__ __launch_bounds__(256, 1) void lstm_pipe_kernel(
    const float* xw1, const float* U1,
    const float* U2, const float* W2, const float* b2,
    const float* U3, const float* W3, const float* b3,
    const float* g1, const float* be1, const float* m1, const float* v1,
    const float* g2, const float* be2, const float* m2, const float* v2,
    float* h1r, float* h2r, float* xz2r, float* xz3r, float* h3,
    int* f)
{
    extern __shared__ float smem[];
    int* f_h1  = f +   0;
    int* d_p2  = f +  32;
    int* f_xz2 = f +  64;
    int* d_r2  = f +  96;
    int* f_h2  = f + 128;
    int* d_p3  = f + 160;
    int* f_xz3 = f + 192;
    int* d_r3  = f + 224;

    switch (blockIdx.x) {
    case 0: rec_role(xw1, 0, U1, h1r, RN, 1, (int*)0, (int*)0, d_p2, f_h1, smem); break;
    case 1: proj_role(h1r, W2, b2, g1, be1, m1, v1, xz2r, f_h1, d_p2, d_r2, f_xz2, smem); break;
    case 2: rec_role(xz2r, 1, U2, h2r, RN, 1, f_xz2, d_r2, d_p3, f_h2, smem); break;
    case 3: proj_role(h2r, W3, b3, g2, be2, m2, v2, xz3r, f_h2, d_p3, d_r3, f_xz3, smem); break;
    case 4: rec_role(xz3r, 1, U3, h3, T_STEPS, 0, f_xz3, d_r3, (int*)0, (int*)0, smem); break;
    }
}

// ---------------------------------------------------------------------------
// Dense (100->3) + softmax, BN3 folded.  H is TRANSPOSED [100][T] -> the
// per-k read h[k*T+row] is perfectly coalesced across threads (rows).
// ---------------------------------------------------------------------------
__global__ __launch_bounds__(256) void dense_softmax_kernel(
    const float* __restrict__ H,    // [100][T] raw h3 (transposed)
    const float* __restrict__ Wd,
    const float* __restrict__ bd,
    const float* __restrict__ g3, const float* __restrict__ be3,
    const float* __restrict__ m3, const float* __restrict__ v3,
    float* __restrict__ out, int T)
{
    __shared__ float w[300];
    __shared__ float b[3];
    const int tid = threadIdx.x;
    for (int i = tid; i < 300; i += 256) {
        int k = i / 3;
        float sc = g3[k] * rsqrtf(v3[k] + 1e-3f);
        w[i] = Wd[i] * sc;
    }
    if (tid < 3) {
        float acc = bd[tid];
        for (int k = 0; k < NU; ++k) {
            float sc = g3[k] * rsqrtf(v3[k] + 1e-3f);
            float sh = be3[k] - m3[k] * sc;
            acc += sh * Wd[3 * k + tid];
        }
        b[tid] = acc;
    }
    __syncthreads();

    int row = blockIdx.x * blockDim.x + tid;
    if (row >= T) return;
    float s0 = b[0], s1 = b[1], s2 = b[2];
    #pragma unroll 4
    for (int k = 0; k < NU; ++k) {
        float hv = H[(long)k * T + row];
        s0 += hv * w[3 * k + 0];
        s1 += hv * w[3 * k + 1];
        s2 += hv * w[3 * k + 2];
    }
    float mx = fmaxf(s0, fmaxf(s1, s2));
    float e0 = __expf(s0 - mx), e1 = __expf(s1 - mx), e2 = __expf(s2 - mx);
    float inv = 1.f / (e0 + e1 + e2);
    out[(long)row * 3 + 0] = e0 * inv;
    out[(long)row * 3 + 1] = e1 * inv;
    out[(long)row * 3 + 2] = e2 * inv;
}

// ---------------------------------------------------------------------------
extern "C" void kernel_launch(void* const* d_in, const int* in_sizes, int n_in,
                              void* d_out, int out_size, void* d_ws, size_t ws_size,
                              hipStream_t stream)
{
    const float* x   = (const float*)d_in[0];
    const float* W1  = (const float*)d_in[1];
    const float* U1  = (const float*)d_in[2];
    const float* b1  = (const float*)d_in[3];
    const float* ga1 = (const float*)d_in[4];
    const float* be1 = (const float*)d_in[5];
    const float* mu1 = (const float*)d_in[6];
    const float* va1 = (const float*)d_in[7];
    const float* W2  = (const float*)d_in[8];
    const float* U2  = (const float*)d_in[9];
    const float* b2  = (const float*)d_in[10];
    const float* ga2 = (const float*)d_in[11];
    const float* be2 = (const float*)d_in[12];
    const float* mu2 = (const float*)d_in[13];
    const float* va2 = (const float*)d_in[14];
    const float* W3  = (const float*)d_in[15];
    const float* U3  = (const float*)d_in[16];
    const float* b3  = (const float*)d_in[17];
    const float* ga3 = (const float*)d_in[18];
    const float* be3 = (const float*)d_in[19];
    const float* mu3 = (const float*)d_in[20];
    const float* va3 = (const float*)d_in[21];
    const float* Wd  = (const float*)d_in[22];
    const float* bd  = (const float*)d_in[23];

    // workspace layout (floats) — total ~51.9 MB (same as R9)
    float* xw1  = (float*)d_ws;                       // T*400 (permuted)
    float* h3   = xw1  + (size_t)T_STEPS * NG;        // [100][T] transposed
    float* h1r  = h3   + (size_t)T_STEPS * NU;        // [100][RN] transposed ring
    float* h2r  = h1r  + (size_t)RN * NU;
    float* xz2r = h2r  + (size_t)RN * NU;             // RN*400 (permuted)
    float* xz3r = xz2r + (size_t)RN * NG;
    int*   flags = (int*)(xz3r + (size_t)RN * NG);    // 512 ints
    float* out = (float*)d_out;

    dim3 blk(256);
    dim3 grd((NG + 63) / 64, (T_STEPS + 63) / 64);

    // 1) input projection of layer 1 (permuted-column output)
    gemm_bias_kernel<<<grd, blk, 0, stream>>>(x, W1, b1, xw1, T_STEPS, NG, DIN);
    // 2) zero the pipeline flags
    hipMemsetAsync(flags, 0, 512 * sizeof(int), stream);
    // 3) persistent pipeline: 5 blocks x 256 threads, 99.8 KB dynamic LDS
    lstm_pipe_kernel<<<5, 256, CHUNK * KPAD * sizeof(float), stream>>>(
        xw1, U1, U2, W2, b2, U3, W3, b3,
        ga1, be1, mu1, va1, ga2, be2, mu2, va2,
        h1r, h2r, xz2r, xz3r, h3, flags);
    // 4) dense + softmax (BN3 folded, transposed-H reads)
    dense_softmax_kernel<<<(T_STEPS + 255) / 256, 256, 0, stream>>>(
        h3, Wd, bd, ga3, be3, mu3, va3, out, T_STEPS);
}